// Round 16
// baseline (6272.628 us; speedup 1.0000x reference)
//
#include <hip/hip_runtime.h>

// Net_32323923870241: graph fusion block, MI355X (gfx950)
// Round 16: fused agg-in-GEMM, occupancy-fixed: 64-row tiles, 32KB LDS
// (2x 16KB slot panels; stats/h overlaid) -> 5 blocks/CU, cross-block
// agg/MFMA overlap. Slot-major CSR; B/wc2 frags direct from L2.
// One dispatch per iteration; Xc intermediate eliminated.

#define NN 250000
#define DD 128
#define EE 500000
#define ELE 50000
#define NITER 4
#define NL 14
#define M14 (NL*NN)
#define TOTE (12*EE + 2*ELE)     // 6,100,000 edges
#define KBIG (15*DD)             // 1920
#define TILES_TOTAL ((NN + 127)/128)      // 1954 buckets
#define NBKT TILES_TOTAL
#define BCAP 4096
#define LK (128*NL)              // 1792 local keys per bucket (slot-major)
#define NBLK_BUCKET 512
#define EPB ((TOTE + NBLK_BUCKET - 1)/NBLK_BUCKET)
#define WCAT_ELEMS (128*KBIG)    // 245760
#define WITER (WCAT_ELEMS + 128*128)  // 262144 per iteration
#define PANEL 8192               // 64*128 u16 = 16KB

typedef unsigned short u16;
typedef __attribute__((ext_vector_type(4))) float f32x4;
typedef __attribute__((ext_vector_type(8))) __bf16 bf16x8;

static __device__ __forceinline__ unsigned f2bf(float f) {
  unsigned u = __float_as_uint(f);
  return (u + 0x7fffu + ((u >> 16) & 1u)) >> 16;   // RNE
}
static __device__ __forceinline__ float bflo(unsigned w){ return __uint_as_float(w << 16); }
static __device__ __forceinline__ float bfhi(unsigned w){ return __uint_as_float(w & 0xffff0000u); }

static __device__ __forceinline__ void gload16(const u16* g, u16* l) {
  __builtin_amdgcn_global_load_lds(
      (const __attribute__((address_space(1))) void*)g,
      (__attribute__((address_space(3))) void*)l, 16, 0, 0);
}

static __device__ __forceinline__ int edge_u(int idx,
    const int* __restrict__ pu, const int* __restrict__ su,
    const int* __restrict__ lu, const int* __restrict__ ru) {
  if (idx < 12*EE) {
    int l = idx / EE; int e = idx - l*EE;
    return (l < 6) ? pu[l*EE + e] : su[(l-6)*EE + e];
  }
  int r = idx - 12*EE;
  return (r < ELE) ? lu[r] : ru[r - ELE];
}

static __device__ __forceinline__ void edge_luv(int idx,
    const int* __restrict__ pu, const int* __restrict__ pv,
    const int* __restrict__ su, const int* __restrict__ sv,
    const int* __restrict__ lu, const int* __restrict__ lv,
    const int* __restrict__ ru, const int* __restrict__ rv,
    int& l, int& u, int& v) {
  if (idx < 12*EE) {
    l = idx / EE; int e = idx - l*EE;
    if (l < 6) { u = pu[l*EE+e]; v = pv[l*EE+e]; }
    else       { u = su[(l-6)*EE+e]; v = sv[(l-6)*EE+e]; }
  } else {
    int r = idx - 12*EE;
    if (r < ELE) { l = 12; u = lu[r]; v = lv[r]; }
    else         { l = 13; u = ru[r-ELE]; v = rv[r-ELE]; }
  }
}

// ---------------- CSR build (slot-major local keys) ----------------
__global__ __launch_bounds__(1024) void k_bucket(
    const int* __restrict__ pu, const int* __restrict__ pv,
    const int* __restrict__ su, const int* __restrict__ sv,
    const int* __restrict__ lu, const int* __restrict__ lv,
    const int* __restrict__ ru, const int* __restrict__ rv,
    int* __restrict__ bcur, unsigned* __restrict__ bstage) {
  __shared__ int cnt[NBKT];
  __shared__ int cur[NBKT];
  int t = threadIdx.x;
  for (int i=t; i<NBKT; i+=1024) cnt[i] = 0;
  __syncthreads();
  int e0 = blockIdx.x * EPB;
  int e1 = e0 + EPB; if (e1 > TOTE) e1 = TOTE;
  for (int idx = e0 + t; idx < e1; idx += 1024) {
    int u = edge_u(idx, pu, su, lu, ru);
    atomicAdd(&cnt[u >> 7], 1);
  }
  __syncthreads();
  for (int i=t; i<NBKT; i+=1024) {
    int c = cnt[i];
    cur[i] = c ? atomicAdd(&bcur[i], c) : 0;
  }
  __syncthreads();
  for (int idx = e0 + t; idx < e1; idx += 1024) {
    int l, u, v;
    edge_luv(idx, pu, pv, su, sv, lu, lv, ru, rv, l, u, v);
    int b = u >> 7;
    unsigned rec = ((unsigned)((l << 7) | (u & 127)) << 18) | (unsigned)v;
    int pos = atomicAdd(&cur[b], 1);
    if (pos < BCAP) bstage[(size_t)b*BCAP + pos] = rec;
  }
}

__global__ void k_bscan(const int* __restrict__ bcur, int* __restrict__ bbase,
                        int* __restrict__ rowptr) {
  __shared__ int wsum[4];
  int t = threadIdx.x, lane = t & 63, w = t >> 6;
  int v[8]; int s = 0;
  #pragma unroll
  for (int j=0;j<8;j++){
    int idx = t*8 + j;
    int x = 0;
    if (idx < NBKT) { x = bcur[idx]; if (x > BCAP) x = BCAP; }
    v[j] = s; s += x;
  }
  int ps = s;
  for (int d=1; d<64; d<<=1) { int o = __shfl_up(ps, d); if (lane >= d) ps += o; }
  if (lane == 63) wsum[w] = ps;
  __syncthreads();
  int woff = 0;
  for (int j=0;j<w;j++) woff += wsum[j];
  int excl = woff + ps - s;
  #pragma unroll
  for (int j=0;j<8;j++){
    int idx = t*8 + j;
    if (idx < NBKT) bbase[idx] = excl + v[j];
  }
  if (t == 255) rowptr[M14] = excl + s;
}

// one block per bucket: local hist + scan -> rowptr + placed edges.
// edge_v record: (row_in_bucket << 18) | v
__global__ __launch_bounds__(256) void k_place(const unsigned* __restrict__ bstage,
    const int* __restrict__ bcur, const int* __restrict__ bbase,
    int* __restrict__ rowptr, unsigned* __restrict__ edge_v) {
  __shared__ int lh[LK];
  __shared__ int lex[LK];
  __shared__ int wsum[4];
  int b = blockIdx.x, t = threadIdx.x;
  int lane = t & 63, w = t >> 6;
  int cnt = bcur[b]; if (cnt > BCAP) cnt = BCAP;
  int base = bbase[b];
  const unsigned* rec = bstage + (size_t)b*BCAP;
  for (int i=t; i<LK; i+=256) lh[i] = 0;
  __syncthreads();
  for (int e=t; e<cnt; e+=256) atomicAdd(&lh[rec[e]>>18], 1);
  __syncthreads();
  int s = 0;
  int my[7];
  #pragma unroll
  for (int j=0;j<7;j++){ my[j] = s; s += lh[t*7+j]; }
  int ps = s;
  for (int d=1; d<64; d<<=1) { int o = __shfl_up(ps, d); if (lane >= d) ps += o; }
  if (lane == 63) wsum[w] = ps;
  __syncthreads();
  int woff = 0;
  for (int j=0;j<w;j++) woff += wsum[j];
  int excl = woff + ps - s;
  #pragma unroll
  for (int j=0;j<7;j++) lex[t*7+j] = excl + my[j];
  __syncthreads();
  for (int i=t; i<LK; i+=256) rowptr[(size_t)b*LK + i] = base + lex[i];
  for (int i=t; i<LK; i+=256) lh[i] = lex[i];
  __syncthreads();
  for (int e=t; e<cnt; e+=256) {
    unsigned r = rec[e];
    unsigned key = r >> 18;
    int pos = atomicAdd(&lh[key], 1);
    edge_v[base + pos] = ((key & 127u) << 18) | (r & 0x3FFFFu);
  }
}

// ---------------- setup kernels ----------------
__global__ void k_f2bf(const float* __restrict__ in, unsigned* __restrict__ out) {
  int i = blockIdx.x*256 + threadIdx.x;
  float2 v = ((const float2*)in)[i];
  out[i] = f2bf(v.x) | (f2bf(v.y) << 16);
}

// Precompute wcat/wc2 for ALL 4 iterations in one dispatch.
__global__ void k_bw(const float* __restrict__ Wc, const float* __restrict__ Wp,
                     const float* __restrict__ Ws, const float* __restrict__ Wl,
                     const float* __restrict__ Wr, const float* __restrict__ Wc2,
                     u16* __restrict__ wcat4, u16* __restrict__ wc24) {
  int gi = blockIdx.x*256 + threadIdx.x;
  int it = gi / WITER;
  int i  = gi - it*WITER;
  if (i < WCAT_ELEMS) {
    int r = i / KBIG, K = i - r*KBIG;
    int s = K >> 7, c = K & 127;
    float val;
    if (s == 0)       val = Wc[(it*128 + r)*128 + c];
    else if (s <= 6)  val = Wp[((it*6 + (s-1))*128 + r)*128 + c];
    else if (s <= 12) val = Ws[((it*6 + (s-7))*128 + r)*128 + c];
    else if (s == 13) val = Wl[(it*128 + r)*128 + c];
    else              val = Wr[(it*128 + r)*128 + c];
    wcat4[(size_t)it*WCAT_ELEMS + i] = (u16)f2bf(val);
  } else {
    int j = i - WCAT_ELEMS;
    wc24[(size_t)it*16384 + j] = (u16)f2bf(Wc2[it*16384 + j]);
  }
}

// Fused 64-row tile: slot0 staged from fbf; slots1..14 aggregated from CSR
// into double-buffered 16KB panels (wave = 16-row span, slot-major CSR);
// MFMA consumes previous panel with B-frags direct from L2. Then GN1+ReLU ->
// h(panel1) -> GEMM2(wc2 direct) -> GN2+res+ReLU -> fout/out32.
__global__ __launch_bounds__(256) void gemm_fused(
    const unsigned* __restrict__ fbf, const u16* __restrict__ Bw,
    const u16* __restrict__ wc2g,
    const int* __restrict__ rowptr, const unsigned* __restrict__ edge_v,
    unsigned* __restrict__ fout, float* __restrict__ out32, int last,
    const float* __restrict__ g1w, const float* __restrict__ g1b,
    const float* __restrict__ g2w, const float* __restrict__ g2b) {
  __shared__ u16 smem[2*PANEL];         // exactly 32KB -> 5 blocks/CU
  int tid = threadIdx.x, wid = tid >> 6, lane = tid & 63;
  int wm = wid >> 1, wn = wid & 1;
  int g = lane >> 4, l15 = lane & 15, l7 = lane & 7;
  int b = blockIdx.x >> 1;              // bucket
  int h = blockIdx.x & 1;               // half (64 rows)
  int tile_base = b*128 + h*64;         // first node of this tile

  // ---- prologue: stage slot 0 (self rows) into panel 0, pre-swizzled src
  #pragma unroll
  for (int j=0;j<4;j++) {
    int rb = j*16 + wid*4;
    int r = rb + (lane>>4);
    int arow = tile_base + r; if (arow > NN-1) arow = NN-1;
    gload16((const u16*)fbf + (size_t)arow*128 + (((lane&15) ^ (r&7))<<3),
            smem + rb*128);
  }

  f32x4 acc[2][4] = {};
  // ---- K-loop over 15 slots
  for (int s = 0; s < 15; ++s) {
    if (s < 14) {
      // aggregate slot s+1 (list s) into panel (s+1)&1; wave owns 16 rows
      u16* dst = smem + (((s+1)&1) ? PANEL : 0);
      int base_r = wid*16;              // row-in-tile
      size_t rpb = (size_t)b*LK + s*128 + h*64 + base_r;
      int st0 = rowptr[rpb];
      int en  = rowptr[rpb + 16];
      float ax = 0.f, ay = 0.f;
      int cur = base_r;
      unsigned recs = 0;
      for (int eb = st0; eb < en; eb += 16) {
        int off = (eb - st0) & 63;
        if (off == 0) { int e = eb + lane; recs = (e < en) ? edge_v[e] : 0u; }
        int m = en - eb; if (m > 16) m = 16;
        unsigned wrow[16]; int rr[16];
        #pragma unroll
        for (int q=0;q<16;q++) if (q < m) {
          unsigned rq = __shfl(recs, off + q);
          rr[q] = (int)(rq >> 18) - h*64;
          wrow[q] = fbf[(size_t)(rq & 0x3FFFFu)*64 + lane];
        }
        #pragma unroll
        for (int q=0;q<16;q++) if (q < m) {
          int r = rr[q];
          while (cur < r) {
            *(unsigned*)&dst[(cur*128 + 2*lane) ^ ((cur&7)<<3)] =
                f2bf(ax) | (f2bf(ay) << 16);
            ax = 0.f; ay = 0.f; cur++;
          }
          ax += bflo(wrow[q]); ay += bfhi(wrow[q]);
        }
      }
      while (cur < base_r + 16) {
        *(unsigned*)&dst[(cur*128 + 2*lane) ^ ((cur&7)<<3)] =
            f2bf(ax) | (f2bf(ay) << 16);
        ax = 0.f; ay = 0.f; cur++;
      }
    }
    __syncthreads();                    // panel s ready (stage/agg drained)
    const u16* abuf = smem + ((s&1) ? PANEL : 0);
    #pragma unroll
    for (int kk=0; kk<4; kk++) {
      bf16x8 af[2], wf[4];
      #pragma unroll
      for (int nt=0; nt<4; nt++)
        wf[nt] = *(const bf16x8*)&Bw[(size_t)(wn*64 + nt*16 + l15)*KBIG + s*128 + kk*32 + g*8];
      #pragma unroll
      for (int mt=0; mt<2; mt++)
        af[mt] = *(const bf16x8*)&abuf[((wm*32 + mt*16 + l15)*128 + kk*32 + g*8) ^ (l7<<3)];
      #pragma unroll
      for (int mt=0; mt<2; mt++)
        #pragma unroll
        for (int nt=0; nt<4; nt++)
          acc[mt][nt] = __builtin_amdgcn_mfma_f32_16x16x32_bf16(af[mt], wf[nt], acc[mt][nt], 0, 0, 0);
    }
    __syncthreads();                    // done reading panel s&1
  }

  float* stats = (float*)smem;          // panel0 start (free after K-loop)
  u16* hbuf = smem + PANEL;             // h panel = panel1

  // ---- GN1 stats
  #pragma unroll
  for (int mt=0; mt<2; mt++)
    #pragma unroll
    for (int r=0; r<4; r++) {
      float s = 0.f, q = 0.f;
      #pragma unroll
      for (int nt=0; nt<4; nt++) { float v = acc[mt][nt][r]; s += v; q += v*v; }
      #pragma unroll
      for (int d=1; d<16; d<<=1) { s += __shfl_xor(s, d); q += __shfl_xor(q, d); }
      if (l15 == 0) {
        int R = wm*32 + mt*16 + g*4 + r;
        stats[(wn*64 + R)*2 + 0] = s; stats[(wn*64 + R)*2 + 1] = q;
      }
    }
  __syncthreads();

  // ---- h = relu(GN1(acc)) -> hbuf (swizzled bf16 pairs)
  float w1[4], b1[4], w2[4], b2[4];
  #pragma unroll
  for (int nt=0; nt<4; nt++) {
    int C = wn*64 + nt*16 + l15;
    w1[nt] = g1w[C]; b1[nt] = g1b[C];
    w2[nt] = g2w[C]; b2[nt] = g2b[C];
  }
  #pragma unroll
  for (int mt=0; mt<2; mt++)
    #pragma unroll
    for (int r=0; r<4; r++) {
      int R = wm*32 + mt*16 + g*4 + r;
      float ts = stats[R*2] + stats[(64+R)*2];
      float tq = stats[R*2+1] + stats[(64+R)*2+1];
      float mu = ts*(1.f/DD), var = tq*(1.f/DD) - mu*mu;
      float rs = rsqrtf(var + 1e-5f);
      #pragma unroll
      for (int nt=0; nt<4; nt++) {
        int C = wn*64 + nt*16 + l15;
        float y = fmaxf(fmaf((acc[mt][nt][r]-mu)*rs, w1[nt], b1[nt]), 0.f);
        float p = __shfl_xor(y, 1);
        if (!(lane & 1)) {
          unsigned word = f2bf(y) | (f2bf(p) << 16);
          *(unsigned*)&hbuf[(R*128 + (C & ~1)) ^ ((R&7)<<3)] = word;
        }
      }
    }
  __syncthreads();

  // ---- GEMM2: a2 = h @ wc2^T (wc2 direct from L2)
  f32x4 a2[2][4] = {};
  #pragma unroll
  for (int kk2=0; kk2<4; kk2++) {
    bf16x8 wf[4], hf[2];
    #pragma unroll
    for (int nt=0; nt<4; nt++)
      wf[nt] = *(const bf16x8*)&wc2g[(size_t)(wn*64 + nt*16 + l15)*DD + kk2*32 + g*8];
    #pragma unroll
    for (int mt=0; mt<2; mt++)
      hf[mt] = *(const bf16x8*)&hbuf[((wm*32 + mt*16 + l15)*128 + kk2*32 + g*8) ^ (l7<<3)];
    #pragma unroll
    for (int mt=0; mt<2; mt++)
      #pragma unroll
      for (int nt=0; nt<4; nt++)
        a2[mt][nt] = __builtin_amdgcn_mfma_f32_16x16x32_bf16(hf[mt], wf[nt], a2[mt][nt], 0, 0, 0);
  }
  __syncthreads();

  // ---- GN2 stats
  #pragma unroll
  for (int mt=0; mt<2; mt++)
    #pragma unroll
    for (int r=0; r<4; r++) {
      float s = 0.f, q = 0.f;
      #pragma unroll
      for (int nt=0; nt<4; nt++) { float v = a2[mt][nt][r]; s += v; q += v*v; }
      #pragma unroll
      for (int d=1; d<16; d<<=1) { s += __shfl_xor(s, d); q += __shfl_xor(q, d); }
      if (l15 == 0) {
        int R = wm*32 + mt*16 + g*4 + r;
        stats[(wn*64 + R)*2 + 0] = s; stats[(wn*64 + R)*2 + 1] = q;
      }
    }
  __syncthreads();

  // ---- final: relu(GN2 + res) -> fout (+ out32 on last iter)
  #pragma unroll
  for (int mt=0; mt<2; mt++)
    #pragma unroll
    for (int r=0; r<4; r++) {
      int R = wm*32 + mt*16 + g*4 + r;
      int grow = tile_base + R;
      float ts = stats[R*2] + stats[(64+R)*2];
      float tq = stats[R*2+1] + stats[(64+R)*2+1];
      float mu = ts*(1.f/DD), var = tq*(1.f/DD) - mu*mu;
      float rs = rsqrtf(var + 1e-5f);
      bool ok = grow < NN;
      #pragma unroll
      for (int nt=0; nt<4; nt++) {
        int C = wn*64 + nt*16 + l15;
        float yv = fmaf((a2[mt][nt][r]-mu)*rs, w2[nt], b2[nt]);
        unsigned rw = ok ? fbf[(size_t)grow*64 + (C>>1)] : 0u;
        float resv = (lane & 1) ? bfhi(rw) : bflo(rw);
        float o = fmaxf(yv + resv, 0.f);
        if (last && ok) out32[(size_t)grow*DD + C] = o;
        float p = __shfl_xor(o, 1);
        if (!(lane & 1) && ok)
          fout[(size_t)grow*64 + (C>>1)] = f2bf(o) | (f2bf(p) << 16);
      }
    }
}

extern "C" void kernel_launch(void* const* d_in, const int* in_sizes, int n_in,
                              void* d_out, int out_size, void* d_ws, size_t ws_size,
                              hipStream_t stream) {
  const float* feat_in = (const float*)d_in[0];
  const int* pre_u  = (const int*)d_in[1];
  const int* pre_v  = (const int*)d_in[2];
  const int* suc_u  = (const int*)d_in[3];
  const int* suc_v  = (const int*)d_in[4];
  const int* left_u = (const int*)d_in[5];
  const int* left_v = (const int*)d_in[6];
  const int* right_u= (const int*)d_in[7];
  const int* right_v= (const int*)d_in[8];
  const float* W_ctr  = (const float*)d_in[9];
  const float* W_pre  = (const float*)d_in[10];
  const float* W_suc  = (const float*)d_in[11];
  const float* W_left = (const float*)d_in[12];
  const float* W_right= (const float*)d_in[13];
  const float* gn1w   = (const float*)d_in[14];
  const float* gn1b   = (const float*)d_in[15];
  const float* W_ctr2 = (const float*)d_in[16];
  const float* gn2w   = (const float*)d_in[17];
  const float* gn2b   = (const float*)d_in[18];

  char* ws = (char*)d_ws;
  size_t off = 0;
  auto alloc = [&](size_t bytes) -> char* {
    char* p = ws + off; off += (bytes + 255) & ~(size_t)255; return p;
  };
  unsigned* featA  = (unsigned*)alloc((size_t)NN*64*4);                  // 64 MB
  unsigned* featB  = (unsigned*)alloc((size_t)NN*64*4);                  // 64 MB
  u16*      wcat4  = (u16*)     alloc((size_t)NITER*WCAT_ELEMS*2);       // 2 MB
  u16*      wc24   = (u16*)     alloc((size_t)NITER*128*128*2);
  int*      rowptr = (int*)     alloc(((size_t)NBKT*LK + 1)*4);          // 14 MB
  unsigned* edge_v = (unsigned*)alloc((size_t)(TOTE + 64)*4);            // 24.4 MB
  unsigned* bstage = (unsigned*)alloc((size_t)NBKT*BCAP*4);              // 32 MB
  int*      bcur   = (int*)     alloc((size_t)NBKT*4);
  int*      bbase  = (int*)     alloc((size_t)NBKT*4);
  (void)in_sizes; (void)n_in; (void)out_size; (void)ws_size;

  // ---- CSR build (edges iteration-invariant) + all-iteration weight prep ----
  (void)hipMemsetAsync(bcur, 0, (size_t)NBKT*4, stream);
  k_bucket<<<NBLK_BUCKET, 1024, 0, stream>>>(pre_u, pre_v, suc_u, suc_v,
                                             left_u, left_v, right_u, right_v,
                                             bcur, bstage);
  k_bscan<<<1, 256, 0, stream>>>(bcur, bbase, rowptr);
  k_place<<<NBKT, 256, 0, stream>>>(bstage, bcur, bbase, rowptr, edge_v);
  k_bw<<<(NITER*WITER)/256, 256, 0, stream>>>(W_ctr, W_pre, W_suc, W_left, W_right,
                                              W_ctr2, wcat4, wc24);
  k_f2bf<<<NN*64/256, 256, 0, stream>>>(feat_in, featA);

  for (int it = 0; it < NITER; it++) {
    unsigned* fin = (it & 1) ? featB : featA;
    unsigned* fo  = (it & 1) ? featA : featB;
    int last = (it == NITER-1) ? 1 : 0;
    const u16* wcat = wcat4 + (size_t)it*WCAT_ELEMS;
    const u16* wc2  = wc24  + (size_t)it*16384;
    gemm_fused<<<2*NBKT, 256, 0, stream>>>(fin, wcat, wc2, rowptr, edge_v,
                                           fo, (float*)d_out, last,
                                           gn1w + it*DD, gn1b + it*DD,
                                           gn2w + it*DD, gn2b + it*DD);
  }
}

// Round 17
// 4199.158 us; speedup vs baseline: 1.4938x; 1.4938x over previous
//
#include <hip/hip_runtime.h>

// Net_32323923870241: graph fusion block, MI355X (gfx950)
// FINAL (round 13 verified, 4205us): split pipeline.
//  - CSR via bucketed counting sort (two-pass LDS-histogram binning)
//  - k_agg: wave-per-node, depth-16 statically-indexed gather pipeline
//  - gemm_fused: 64x128 tile (2 blocks/CU), swizzled LDS staging, fused
//    GN1+ReLU -> h(LDS) -> GEMM2 -> GN2+residual+ReLU, bf16 ping-pong feat.

#define NN 250000
#define DD 128
#define EE 500000
#define ELE 50000
#define NITER 4
#define NL 14
#define M14 (NL*NN)              // 3,500,000
#define TOTE (12*EE + 2*ELE)     // 6,100,000 edges
#define KBIG (15*DD)             // 1920
#define BK 64
#define TILES_TOTAL ((NN + 127)/128)      // 1954 (128-row tiles)
#define NBKT TILES_TOTAL
#define BCAP 4096
#define LK (128*NL)              // 1792 local keys per bucket
#define NBLK_BUCKET 256
#define EPB ((TOTE + NBLK_BUCKET - 1)/NBLK_BUCKET)   // 23829

typedef unsigned short u16;
typedef __attribute__((ext_vector_type(4))) float f32x4;
typedef __attribute__((ext_vector_type(8))) __bf16 bf16x8;

static __device__ __forceinline__ unsigned f2bf(float f) {
  unsigned u = __float_as_uint(f);
  return (u + 0x7fffu + ((u >> 16) & 1u)) >> 16;   // RNE
}
static __device__ __forceinline__ float bflo(unsigned w){ return __uint_as_float(w << 16); }
static __device__ __forceinline__ float bfhi(unsigned w){ return __uint_as_float(w & 0xffff0000u); }

static __device__ __forceinline__ void gload16(const u16* g, u16* l) {
  __builtin_amdgcn_global_load_lds(
      (const __attribute__((address_space(1))) void*)g,
      (__attribute__((address_space(3))) void*)l, 16, 0, 0);
}

static __device__ __forceinline__ int edge_u(int idx,
    const int* __restrict__ pu, const int* __restrict__ su,
    const int* __restrict__ lu, const int* __restrict__ ru) {
  if (idx < 12*EE) {
    int l = idx / EE; int e = idx - l*EE;
    return (l < 6) ? pu[l*EE + e] : su[(l-6)*EE + e];
  }
  int r = idx - 12*EE;
  return (r < ELE) ? lu[r] : ru[r - ELE];
}

static __device__ __forceinline__ void edge_luv(int idx,
    const int* __restrict__ pu, const int* __restrict__ pv,
    const int* __restrict__ su, const int* __restrict__ sv,
    const int* __restrict__ lu, const int* __restrict__ lv,
    const int* __restrict__ ru, const int* __restrict__ rv,
    int& l, int& u, int& v) {
  if (idx < 12*EE) {
    l = idx / EE; int e = idx - l*EE;
    if (l < 6) { u = pu[l*EE+e]; v = pv[l*EE+e]; }
    else       { u = su[(l-6)*EE+e]; v = sv[(l-6)*EE+e]; }
  } else {
    int r = idx - 12*EE;
    if (r < ELE) { l = 12; u = lu[r]; v = lv[r]; }
    else         { l = 13; u = ru[r-ELE]; v = rv[r-ELE]; }
  }
}

// ---------------- CSR build: two-pass LDS-histogram binning ----------------
__global__ __launch_bounds__(1024) void k_bucket(
    const int* __restrict__ pu, const int* __restrict__ pv,
    const int* __restrict__ su, const int* __restrict__ sv,
    const int* __restrict__ lu, const int* __restrict__ lv,
    const int* __restrict__ ru, const int* __restrict__ rv,
    int* __restrict__ bcur, unsigned* __restrict__ bstage) {
  __shared__ int cnt[NBKT];
  __shared__ int cur[NBKT];
  int t = threadIdx.x;
  for (int i=t; i<NBKT; i+=1024) cnt[i] = 0;
  __syncthreads();
  int e0 = blockIdx.x * EPB;
  int e1 = e0 + EPB; if (e1 > TOTE) e1 = TOTE;
  for (int idx = e0 + t; idx < e1; idx += 1024) {
    int u = edge_u(idx, pu, su, lu, ru);
    atomicAdd(&cnt[u >> 7], 1);
  }
  __syncthreads();
  for (int i=t; i<NBKT; i+=1024) {
    int c = cnt[i];
    cur[i] = c ? atomicAdd(&bcur[i], c) : 0;
  }
  __syncthreads();
  for (int idx = e0 + t; idx < e1; idx += 1024) {
    int l, u, v;
    edge_luv(idx, pu, pv, su, sv, lu, lv, ru, rv, l, u, v);
    int b = u >> 7;
    unsigned rec = ((unsigned)((u & 127)*NL + l) << 18) | (unsigned)v;
    int pos = atomicAdd(&cur[b], 1);
    if (pos < BCAP) bstage[(size_t)b*BCAP + pos] = rec;
  }
}

__global__ void k_bscan(const int* __restrict__ bcur, int* __restrict__ bbase,
                        int* __restrict__ rowptr) {
  __shared__ int wsum[4];
  int t = threadIdx.x, lane = t & 63, w = t >> 6;
  int v[8]; int s = 0;
  #pragma unroll
  for (int j=0;j<8;j++){
    int idx = t*8 + j;
    int x = 0;
    if (idx < NBKT) { x = bcur[idx]; if (x > BCAP) x = BCAP; }
    v[j] = s; s += x;
  }
  int ps = s;
  for (int d=1; d<64; d<<=1) { int o = __shfl_up(ps, d); if (lane >= d) ps += o; }
  if (lane == 63) wsum[w] = ps;
  __syncthreads();
  int woff = 0;
  for (int j=0;j<w;j++) woff += wsum[j];
  int excl = woff + ps - s;
  #pragma unroll
  for (int j=0;j<8;j++){
    int idx = t*8 + j;
    if (idx < NBKT) bbase[idx] = excl + v[j];
  }
  if (t == 255) rowptr[M14] = excl + s;
}

// one block per bucket: local hist + scan -> rowptr + placed edges
__global__ __launch_bounds__(256) void k_place(const unsigned* __restrict__ bstage,
    const int* __restrict__ bcur, const int* __restrict__ bbase,
    int* __restrict__ rowptr, int* __restrict__ edge_v) {
  __shared__ int lh[LK];
  __shared__ int lex[LK];
  __shared__ int wsum[4];
  int b = blockIdx.x, t = threadIdx.x;
  int lane = t & 63, w = t >> 6;
  int cnt = bcur[b]; if (cnt > BCAP) cnt = BCAP;
  int base = bbase[b];
  const unsigned* rec = bstage + (size_t)b*BCAP;
  for (int i=t; i<LK; i+=256) lh[i] = 0;
  __syncthreads();
  for (int e=t; e<cnt; e+=256) atomicAdd(&lh[rec[e]>>18], 1);
  __syncthreads();
  int s = 0;
  int my[7];
  #pragma unroll
  for (int j=0;j<7;j++){ my[j] = s; s += lh[t*7+j]; }
  int ps = s;
  for (int d=1; d<64; d<<=1) { int o = __shfl_up(ps, d); if (lane >= d) ps += o; }
  if (lane == 63) wsum[w] = ps;
  __syncthreads();
  int woff = 0;
  for (int j=0;j<w;j++) woff += wsum[j];
  int excl = woff + ps - s;
  #pragma unroll
  for (int j=0;j<7;j++) lex[t*7+j] = excl + my[j];
  __syncthreads();
  for (int i=t; i<LK; i+=256) rowptr[(size_t)b*LK + i] = base + lex[i];
  for (int i=t; i<LK; i+=256) lh[i] = lex[i];
  __syncthreads();
  for (int e=t; e<cnt; e+=256) {
    unsigned r = rec[e];
    int pos = atomicAdd(&lh[r>>18], 1);
    edge_v[base + pos] = (int)(r & 0x3FFFFu);
  }
}

// ---------------- per-iteration kernels ----------------
__global__ void k_f2bf(const float* __restrict__ in, unsigned* __restrict__ out) {
  int i = blockIdx.x*256 + threadIdx.x;
  float2 v = ((const float2*)in)[i];
  out[i] = f2bf(v.x) | (f2bf(v.y) << 16);
}

__global__ void k_bw(const float* __restrict__ Wc, const float* __restrict__ Wp,
                     const float* __restrict__ Ws, const float* __restrict__ Wl,
                     const float* __restrict__ Wr, const float* __restrict__ Wc2,
                     int it, u16* __restrict__ wcat, u16* __restrict__ wc2) {
  int i = blockIdx.x*256 + threadIdx.x;
  if (i < 128*KBIG) {
    int r = i / KBIG, K = i - r*KBIG;
    int s = K >> 7, c = K & 127;
    float val;
    if (s == 0)       val = Wc[(it*128 + r)*128 + c];
    else if (s <= 6)  val = Wp[((it*6 + (s-1))*128 + r)*128 + c];
    else if (s <= 12) val = Ws[((it*6 + (s-7))*128 + r)*128 + c];
    else if (s == 13) val = Wl[(it*128 + r)*128 + c];
    else              val = Wr[(it*128 + r)*128 + c];
    wcat[i] = (u16)f2bf(val);
  } else {
    int j = i - 128*KBIG;
    wc2[j] = (u16)f2bf(Wc2[it*16384 + j]);
  }
}

// wave-per-node aggregation over 14 CSR lists; depth-16 gather pipeline,
// ALL register arrays statically indexed (rule #20) -> stay in VGPRs.
__global__ __launch_bounds__(256) void k_agg(const unsigned* __restrict__ featbf,
    const int* __restrict__ rowptr, const int* __restrict__ edge_v,
    unsigned* __restrict__ X, int chunk_base) {
  int wid = threadIdx.x >> 6, lane = threadIdx.x & 63;
  int nl = blockIdx.x*4 + wid;
  int node = chunk_base + nl;
  size_t xb = (size_t)nl * (14*64);
  if (node >= NN) {
    #pragma unroll
    for (int s=0;s<14;s++) X[xb + s*64 + lane] = 0;
    return;
  }
  int rp = 0;
  if (lane < 15) rp = rowptr[node*NL + lane];
  int st0 = __shfl(rp, 0);
  int cnt = __shfl(rp, 14) - st0;
  float ax = 0.f, ay = 0.f;
  int s = 0;
  int nextb = __shfl(rp, 1);
  int vv = 0;
  for (int base = 0; base < cnt; base += 16) {
    int off = base & 63;
    if (off == 0) vv = edge_v[st0 + base + lane];   // edge_v padded by 64
    int m = cnt - base; if (m > 16) m = 16;
    unsigned wrow[16];
    #pragma unroll
    for (int q=0;q<16;q++) if (q < m) {
      int v = __shfl(vv, off + q);
      wrow[q] = featbf[(size_t)v*64 + lane];
    }
    #pragma unroll
    for (int q=0;q<16;q++) if (q < m) {
      int e = st0 + base + q;
      while (e == nextb && s < 14) {
        X[xb + s*64 + lane] = f2bf(ax) | (f2bf(ay) << 16);
        ax = 0.f; ay = 0.f; s++;
        int ni = s + 1; if (ni > 14) ni = 14;
        nextb = __shfl(rp, ni);
      }
      ax += bflo(wrow[q]); ay += bfhi(wrow[q]);
    }
  }
  while (s < 14) {
    X[xb + s*64 + lane] = f2bf(ax) | (f2bf(ay) << 16);
    ax = 0.f; ay = 0.f; s++;
  }
}

// 64x128 fused tile pipeline: acc = [fbf | Xc] @ wcat^T (K=1920, swizzled
// LDS staging), GN1+ReLU -> h(LDS) -> GEMM2(wc2 from L2) -> GN2+res+ReLU.
// 4 waves: wm=rows(2x32), wn=cols(2x64); acc[2][4]; ~25KB LDS -> 2+ blocks/CU.
__global__ __launch_bounds__(256) void gemm_fused(
    const u16* __restrict__ Xc, const unsigned* __restrict__ fbf,
    const u16* __restrict__ Bw, const u16* __restrict__ wc2g,
    unsigned* __restrict__ fout, float* __restrict__ out32, int last,
    const float* __restrict__ g1w, const float* __restrict__ g1b,
    const float* __restrict__ g2w, const float* __restrict__ g2b,
    int row0_abs) {
  __shared__ u16 smem[64*BK + 128*BK];   // As(8KB)+Bs(16KB); h(16KB) after
  __shared__ float stats[2][64][2];
  u16* As = smem; u16* Bs = smem + 64*BK;
  int tid = threadIdx.x, wid = tid >> 6, lane = tid & 63;
  int wm = wid >> 1, wn = wid & 1;
  int g = lane >> 4, l15 = lane & 15, l7 = lane & 7;
  int tile_row = blockIdx.x * 64;        // chunk-local row base
  f32x4 acc[2][4] = {};
  int srow8 = lane >> 3;
  int scol = ((lane & 7) ^ srow8) * 8;   // pre-swizzled source col (u16)
  for (int k0 = 0; k0 < KBIG; k0 += BK) {
    __syncthreads();
    // 24 1KB segments: 0..7 = A (64 rows), 8..23 = B (128 rows)
    #pragma unroll
    for (int j=0;j<6;j++) {
      int seg = wid + j*4;
      if (seg < 8) {
        int r = seg*8 + srow8;
        if (k0 < DD) {
          int arow = row0_abs + tile_row + r; if (arow > NN-1) arow = NN-1;
          gload16((const u16*)fbf + (size_t)arow*DD + (k0 + scol), &As[seg*512]);
        } else {
          gload16(Xc + (size_t)(tile_row + r)*(14*128) + (k0 - DD + scol), &As[seg*512]);
        }
      } else {
        int sb = seg - 8;
        int r = sb*8 + srow8;
        gload16(Bw + (size_t)r*KBIG + (k0 + scol), &Bs[sb*512]);
      }
    }
    __syncthreads();
    #pragma unroll
    for (int kk=0; kk<2; kk++) {
      bf16x8 af[2], bfr[4];
      #pragma unroll
      for (int mt=0; mt<2; mt++)
        af[mt] = *(const bf16x8*)&As[((wm*32 + mt*16 + l15)*BK + kk*32 + g*8) ^ (l7<<3)];
      #pragma unroll
      for (int nt=0; nt<4; nt++)
        bfr[nt] = *(const bf16x8*)&Bs[((wn*64 + nt*16 + l15)*BK + kk*32 + g*8) ^ (l7<<3)];
      #pragma unroll
      for (int mt=0; mt<2; mt++)
        #pragma unroll
        for (int nt=0; nt<4; nt++)
          acc[mt][nt] = __builtin_amdgcn_mfma_f32_16x16x32_bf16(af[mt], bfr[nt], acc[mt][nt], 0, 0, 0);
    }
  }
  __syncthreads();                      // As/Bs free -> h buffer

  // ---- GN1 stats (rows 0..63)
  #pragma unroll
  for (int mt=0; mt<2; mt++)
    #pragma unroll
    for (int r=0; r<4; r++) {
      float s = 0.f, q = 0.f;
      #pragma unroll
      for (int nt=0; nt<4; nt++) { float v = acc[mt][nt][r]; s += v; q += v*v; }
      #pragma unroll
      for (int d=1; d<16; d<<=1) { s += __shfl_xor(s, d); q += __shfl_xor(q, d); }
      if (l15 == 0) {
        int R = wm*32 + mt*16 + g*4 + r;
        stats[wn][R][0] = s; stats[wn][R][1] = q;
      }
    }
  __syncthreads();

  // ---- h = relu(GN1(acc)) -> smem (swizzled bf16 pairs)
  float w1[4], b1[4], w2[4], b2[4];
  #pragma unroll
  for (int nt=0; nt<4; nt++) {
    int C = wn*64 + nt*16 + l15;
    w1[nt] = g1w[C]; b1[nt] = g1b[C];
    w2[nt] = g2w[C]; b2[nt] = g2b[C];
  }
  #pragma unroll
  for (int mt=0; mt<2; mt++)
    #pragma unroll
    for (int r=0; r<4; r++) {
      int R = wm*32 + mt*16 + g*4 + r;
      float ts = stats[0][R][0] + stats[1][R][0];
      float tq = stats[0][R][1] + stats[1][R][1];
      float mu = ts*(1.f/DD), var = tq*(1.f/DD) - mu*mu;
      float rs = rsqrtf(var + 1e-5f);
      #pragma unroll
      for (int nt=0; nt<4; nt++) {
        int C = wn*64 + nt*16 + l15;
        float y = fmaxf(fmaf((acc[mt][nt][r]-mu)*rs, w1[nt], b1[nt]), 0.f);
        float p = __shfl_xor(y, 1);
        if (!(lane & 1)) {
          unsigned word = f2bf(y) | (f2bf(p) << 16);
          *(unsigned*)&smem[(R*128 + (C & ~1)) ^ ((R&7)<<3)] = word;
        }
      }
    }
  __syncthreads();

  // ---- GEMM2: a2 = h @ wc2^T
  f32x4 a2[2][4] = {};
  #pragma unroll
  for (int kk2=0; kk2<4; kk2++) {
    bf16x8 wf[4], hf[2];
    #pragma unroll
    for (int nt=0; nt<4; nt++)
      wf[nt] = *(const bf16x8*)&wc2g[(size_t)(wn*64 + nt*16 + l15)*DD + kk2*32 + g*8];
    #pragma unroll
    for (int mt=0; mt<2; mt++)
      hf[mt] = *(const bf16x8*)&smem[((wm*32 + mt*16 + l15)*128 + kk2*32 + g*8) ^ (l7<<3)];
    #pragma unroll
    for (int mt=0; mt<2; mt++)
      #pragma unroll
      for (int nt=0; nt<4; nt++)
        a2[mt][nt] = __builtin_amdgcn_mfma_f32_16x16x32_bf16(hf[mt], wf[nt], a2[mt][nt], 0, 0, 0);
  }
  __syncthreads();

  // ---- GN2 stats
  #pragma unroll
  for (int mt=0; mt<2; mt++)
    #pragma unroll
    for (int r=0; r<4; r++) {
      float s = 0.f, q = 0.f;
      #pragma unroll
      for (int nt=0; nt<4; nt++) { float v = a2[mt][nt][r]; s += v; q += v*v; }
      #pragma unroll
      for (int d=1; d<16; d<<=1) { s += __shfl_xor(s, d); q += __shfl_xor(q, d); }
      if (l15 == 0) {
        int R = wm*32 + mt*16 + g*4 + r;
        stats[wn][R][0] = s; stats[wn][R][1] = q;
      }
    }
  __syncthreads();

  // ---- final: relu(GN2 + res) -> fout (+ out32 on last iter)
  #pragma unroll
  for (int mt=0; mt<2; mt++)
    #pragma unroll
    for (int r=0; r<4; r++) {
      int R = wm*32 + mt*16 + g*4 + r;
      int grow = row0_abs + tile_row + R;
      float ts = stats[0][R][0] + stats[1][R][0];
      float tq = stats[0][R][1] + stats[1][R][1];
      float mu = ts*(1.f/DD), var = tq*(1.f/DD) - mu*mu;
      float rs = rsqrtf(var + 1e-5f);
      bool ok = grow < NN;
      #pragma unroll
      for (int nt=0; nt<4; nt++) {
        int C = wn*64 + nt*16 + l15;
        float yv = fmaf((a2[mt][nt][r]-mu)*rs, w2[nt], b2[nt]);
        unsigned rw = ok ? fbf[(size_t)grow*64 + (C>>1)] : 0u;
        float resv = (lane & 1) ? bfhi(rw) : bflo(rw);
        float o = fmaxf(yv + resv, 0.f);
        if (last && ok) out32[(size_t)grow*DD + C] = o;
        float p = __shfl_xor(o, 1);
        if (!(lane & 1) && ok)
          fout[(size_t)grow*64 + (C>>1)] = f2bf(o) | (f2bf(p) << 16);
      }
    }
}

extern "C" void kernel_launch(void* const* d_in, const int* in_sizes, int n_in,
                              void* d_out, int out_size, void* d_ws, size_t ws_size,
                              hipStream_t stream) {
  const float* feat_in = (const float*)d_in[0];
  const int* pre_u  = (const int*)d_in[1];
  const int* pre_v  = (const int*)d_in[2];
  const int* suc_u  = (const int*)d_in[3];
  const int* suc_v  = (const int*)d_in[4];
  const int* left_u = (const int*)d_in[5];
  const int* left_v = (const int*)d_in[6];
  const int* right_u= (const int*)d_in[7];
  const int* right_v= (const int*)d_in[8];
  const float* W_ctr  = (const float*)d_in[9];
  const float* W_pre  = (const float*)d_in[10];
  const float* W_suc  = (const float*)d_in[11];
  const float* W_left = (const float*)d_in[12];
  const float* W_right= (const float*)d_in[13];
  const float* gn1w   = (const float*)d_in[14];
  const float* gn1b   = (const float*)d_in[15];
  const float* W_ctr2 = (const float*)d_in[16];
  const float* gn2w   = (const float*)d_in[17];
  const float* gn2b   = (const float*)d_in[18];

  char* ws = (char*)d_ws;
  size_t off = 0;
  auto alloc = [&](size_t bytes) -> char* {
    char* p = ws + off; off += (bytes + 255) & ~(size_t)255; return p;
  };
  unsigned* featA  = (unsigned*)alloc((size_t)NN*64*4);                  // 64 MB
  unsigned* featB  = (unsigned*)alloc((size_t)NN*64*4);                  // 64 MB
  u16*      wcat   = (u16*)     alloc((size_t)128*KBIG*2);
  u16*      wc2    = (u16*)     alloc((size_t)128*128*2);
  int*      rowptr = (int*)     alloc(((size_t)NBKT*LK + 1)*4);          // 14 MB
  int*      edge_v = (int*)     alloc((size_t)(TOTE + 64)*4);            // 24.4 MB
  unsigned* bstage = (unsigned*)alloc((size_t)NBKT*BCAP*4);              // 32 MB
  int*      bcur   = (int*)     alloc((size_t)NBKT*4);
  int*      bbase  = (int*)     alloc((size_t)NBKT*4);

  size_t tile_bytes = (size_t)128*(14*128)*2;   // 448 KiB per 128-row tile
  size_t avail = (ws_size > off + 65536) ? (ws_size - off - 65536) : 0;
  int chunk_tiles = (int)(avail / tile_bytes);
  if (chunk_tiles > 256) chunk_tiles = 256;     // 112 MB, L3-friendly handoff
  if (chunk_tiles < 8) chunk_tiles = 8;
  u16* Xc = (u16*)alloc((size_t)chunk_tiles * tile_bytes);
  int nchunk = (TILES_TOTAL + chunk_tiles - 1) / chunk_tiles;
  (void)in_sizes; (void)n_in; (void)out_size;

  // ---- CSR build (edges iteration-invariant) ----
  (void)hipMemsetAsync(bcur, 0, (size_t)NBKT*4, stream);
  k_bucket<<<NBLK_BUCKET, 1024, 0, stream>>>(pre_u, pre_v, suc_u, suc_v,
                                             left_u, left_v, right_u, right_v,
                                             bcur, bstage);
  k_bscan<<<1, 256, 0, stream>>>(bcur, bbase, rowptr);
  k_place<<<NBKT, 256, 0, stream>>>(bstage, bcur, bbase, rowptr, edge_v);

  k_f2bf<<<NN*64/256, 256, 0, stream>>>(feat_in, featA);

  for (int it = 0; it < NITER; it++) {
    unsigned* fin = (it & 1) ? featB : featA;
    unsigned* fo  = (it & 1) ? featA : featB;
    int last = (it == NITER-1) ? 1 : 0;
    k_bw<<<1024, 256, 0, stream>>>(W_ctr, W_pre, W_suc, W_left, W_right, W_ctr2, it, wcat, wc2);
    for (int c = 0; c < nchunk; c++) {
      int tile0 = c*chunk_tiles;
      int tiles = (TILES_TOTAL - tile0 < chunk_tiles) ? (TILES_TOTAL - tile0) : chunk_tiles;
      int base  = tile0*128;
      k_agg<<<tiles*32, 256, 0, stream>>>(fin, rowptr, edge_v, (unsigned*)Xc, base);
      gemm_fused<<<tiles*2, 256, 0, stream>>>((const u16*)Xc, fin, wcat, wc2,
                                              fo, (float*)d_out, last,
                                              gn1w + it*DD, gn1b + it*DD,
                                              gn2w + it*DD, gn2b + it*DD, base);
    }
  }
}